// Round 8
// baseline (140.510 us; speedup 1.0000x reference)
//
#include <hip/hip_runtime.h>
#include <math.h>

#define H 8
#define B 8
#define C 512
#define L 1024
#define D 64
#define LDK 72   // padded LDS stride for conv staging / flash epilogue bounce

typedef __attribute__((ext_vector_type(4))) float f32x4;
typedef __attribute__((ext_vector_type(16))) float f32x16;
typedef __attribute__((ext_vector_type(8))) short bf16x8;

static __device__ __forceinline__ short f2bf(float x) {      // RNE
    union { float f; unsigned u; } v; v.f = x;
    unsigned r = v.u + 0x7FFFu + ((v.u >> 16) & 1u);
    return (short)(r >> 16);
}
static __device__ __forceinline__ short f2bf_fast(float x) { // round-half-up
    union { float f; unsigned u; } v; v.f = x;
    return (short)((v.u + 0x8000u) >> 16);
}
static __device__ __forceinline__ int pack2(short a, short b) {
    return (int)((unsigned short)a | ((unsigned)(unsigned short)b << 16));
}
static __device__ __forceinline__ float bfs2f(short v) {
    union { unsigned u; float f; } w; w.u = ((unsigned)(unsigned short)v) << 16;
    return w.f;
}
// async 16B/lane global->LDS DMA; lds base must be wave-uniform.
static __device__ __forceinline__ void async16(const void* g, void* s) {
    __builtin_amdgcn_global_load_lds(
        (const __attribute__((address_space(1))) int*)g,
        (__attribute__((address_space(3))) int*)s, 16, 0, 0);
}

// ---------------------------------------------------------------------------
// Weight prep -> bf16 A-fragment order [((conv*8+h)*3+t)*2+khalf][d][quad][jj].
// wq additionally scaled by (1/sqrt(H))*log2(e) so flash softmax runs in exp2.
// ---------------------------------------------------------------------------
__global__ __launch_bounds__(256) void wprep_kernel(
    const float* __restrict__ wq, const float* __restrict__ wk,
    const float* __restrict__ wv, short* __restrict__ wtg)
{
    int idx = blockIdx.x * 256 + threadIdx.x;       // < 294912
    int jj    = idx & 7;
    int quad  = (idx >> 3) & 3;
    int d     = (idx >> 5) & 63;
    int r     = idx >> 11;
    int khalf = r & 1;  r >>= 1;
    int t     = r % 3;  r /= 3;
    int h     = r & 7;
    int conv  = r >> 3;
    const float* w = (conv == 0) ? wq : (conv == 1) ? wk : wv;
    int j_in = khalf * 32 + quad * 8 + jj;
    float v = w[(h * 64 + d) * 192 + j_in * 3 + t];
    if (conv == 0) v *= 0.51012254f;                // (1/sqrt(8)) * log2(e)
    wtg[idx] = f2bf(v);
}

// ---------------------------------------------------------------------------
// Grouped conv1d as bf16 MFMA. src=0: q->qh, src=1: k->kh+vh.
// Outputs written in flash's LDS-image order (64 rows x 8 chunks(16B),
// chunk ^= row&7). x reads line-coalesced (j,seg); vh bounced via LDS ->
// all-int4 stores.
// ---------------------------------------------------------------------------
__global__ __launch_bounds__(256) void conv_kernel(
    const float* __restrict__ q, const float* __restrict__ k,
    const short* __restrict__ wtg,
    short* __restrict__ qh, short* __restrict__ kh, short* __restrict__ vh)
{
    int bx   = blockIdx.x;
    int tile = bx & 15;
    int h    = (bx >> 4) & 7;
    int b    = (bx >> 7) & 7;
    int src  = bx >> 10;                 // 0: q->qh   1: k->kh+vh

    __shared__ __align__(16) short xT[66 * LDK];   // [p][j], p = l0-1 .. l0+64

    int l0  = tile * 64;
    int tid = threadIdx.x;
    int wave = tid >> 6, lane = tid & 63;
    int n = lane & 15, quad = lane >> 4;

    const float* x  = src ? k : q;
    const float* xb = x + (size_t)(b * C + h * 64) * L + l0;

    int c0 = src ? 1 : 0;
    const short* wb0 = wtg + (size_t)((c0 * 8 + h) * 3 * 2) * 2048;
    bf16x8 wf[3][2], wf2[3][2];
    #pragma unroll
    for (int t = 0; t < 3; t++)
        #pragma unroll
        for (int kk = 0; kk < 2; kk++)
            wf[t][kk] = *(const bf16x8*)(wb0 + (t * 2 + kk) * 2048
                                         + (wave * 16 + n) * 32 + quad * 8);
    if (src) {
        const short* wb1 = wtg + (size_t)((2 * 8 + h) * 3 * 2) * 2048;
        #pragma unroll
        for (int t = 0; t < 3; t++)
            #pragma unroll
            for (int kk = 0; kk < 2; kk++)
                wf2[t][kk] = *(const bf16x8*)(wb1 + (t * 2 + kk) * 2048
                                              + (wave * 16 + n) * 32 + quad * 8);
    }

    {   // interior p=1..64: coalesced (j, seg) mapping, 4 float4 per thread
        #pragma unroll
        for (int s = 0; s < 4; s++) {
            int idx = tid + s * 256;             // < 1024
            int j = idx >> 4, seg = idx & 15;
            float4 v = *(const float4*)(xb + j * L + seg * 4);
            int p = 1 + seg * 4;
            xT[(p + 0) * LDK + j] = f2bf(v.x);
            xT[(p + 1) * LDK + j] = f2bf(v.y);
            xT[(p + 2) * LDK + j] = f2bf(v.z);
            xT[(p + 3) * LDK + j] = f2bf(v.w);
        }
        if (tid < 64) {                          // p=0 (reflect left)
            int gl = (l0 == 0) ? 1 : (l0 - 1);
            xT[0 * LDK + tid] = f2bf(x[(size_t)(b * C + h * 64 + tid) * L + gl]);
        } else if (tid < 128) {                  // p=65 (reflect right)
            int j2 = tid - 64;
            int gl = (l0 + 64 >= L) ? (L - 2) : (l0 + 64);
            xT[65 * LDK + j2] = f2bf(x[(size_t)(b * C + h * 64 + j2) * L + gl]);
        }
    }
    __syncthreads();

    f32x4 acc[4], acc2[4];
    #pragma unroll
    for (int bl = 0; bl < 4; bl++) {
        acc[bl]  = (f32x4){0.f, 0.f, 0.f, 0.f};
        acc2[bl] = (f32x4){0.f, 0.f, 0.f, 0.f};
    }

    #pragma unroll
    for (int bl = 0; bl < 4; bl++) {
        #pragma unroll
        for (int t = 0; t < 3; t++) {
            #pragma unroll
            for (int kk = 0; kk < 2; kk++) {
                bf16x8 bf = *(const bf16x8*)&xT[(bl * 16 + n + t) * LDK
                                                + kk * 32 + quad * 8];
                acc[bl] = __builtin_amdgcn_mfma_f32_16x16x32_bf16(
                    wf[t][kk], bf, acc[bl], 0, 0, 0);
                if (src)
                    acc2[bl] = __builtin_amdgcn_mfma_f32_16x16x32_bf16(
                        wf2[t][kk], bf, acc2[bl], 0, 0, 0);
            }
        }
    }

    int bhh = b * H + h;
    short* o1 = src ? kh : qh;
    {   // qh/kh: rows = l, chunks over d; C layout: d = wave*16+quad*4+r, l = bl*16+n
        short* ob = o1 + ((size_t)(bhh * 16 + tile)) * 4096;
        int ch = wave * 2 + (quad >> 1);             // logical d-chunk
        #pragma unroll
        for (int bl = 0; bl < 4; bl++) {
            int l = bl * 16 + n;
            int phys = ch ^ (l & 7);
            int2 v;
            v.x = pack2(f2bf(acc[bl][0]), f2bf(acc[bl][1]));
            v.y = pack2(f2bf(acc[bl][2]), f2bf(acc[bl][3]));
            *(int2*)&ob[l * 64 + phys * 8 + (quad & 1) * 4] = v;
        }
    }
    if (src) {   // vh: rows = d, chunks over l; bounce via xT -> int4 stores
        __syncthreads();                 // all waves done with xT B-frags
        #pragma unroll
        for (int bl = 0; bl < 4; bl++)
            #pragma unroll
            for (int r = 0; r < 4; r++) {
                int d = wave * 16 + quad * 4 + r;
                int l = bl * 16 + n;
                int phys = (bl * 2 + (n >> 3)) ^ (d & 7);
                xT[d * 64 + phys * 8 + (n & 7)] = f2bf(acc2[bl][r]);
            }
        __syncthreads();
        short* vb = vh + ((size_t)(bhh * 16 + tile)) * 4096;
        #pragma unroll
        for (int jj = 0; jj < 2; jj++) {
            int i = tid + jj * 256;      // < 512
            *(int4*)(vb + i * 8) = *(const int4*)&xT[i * 8];
        }
    }
}

// ---------------------------------------------------------------------------
// Causal flash attention, 32x32x16 bf16 MFMA. WG = 128 threads, 2 waves x
// 32 q-rows. Computes S^T (A = K from LDS, B = Q in regs) so the C/D layout
// gives each lane a fixed qrow (col=lane&31) with keys in consecutive
// reg-quads -> P written as packed b64, re-read as PV's A-operand.
// Async DMA double-buffered K/V, one barrier per tile. Constant-shift
// softmax (p = exp2(s-20)); row-sums via ones-MFMA. o -> ot[B,C,L] bf16.
// LDS 40KB -> 4 WG/CU.
// ---------------------------------------------------------------------------
__global__ __launch_bounds__(128, 2) void flash_kernel(
    const short* __restrict__ qh, const short* __restrict__ kh,
    const short* __restrict__ vh, short* __restrict__ ot)
{
    __shared__ __align__(16) short lds[20480];

    int bx = blockIdx.x;
    int bh = bx & 63;
    int qt = 15 - (bx >> 6);             // heavy tiles dispatch first
    int h  = bh & 7, b = bh >> 3;

    int tid  = threadIdx.x;
    int wave = tid >> 6;
    int lane = tid & 63;
    int m    = lane & 31;                // row/col within 32-block
    int half = lane >> 5;                // k-half selector
    int sw   = m & 7;                    // chunk swizzle key

    const short* Qg    = qh + ((size_t)(bh * 16 + qt)) * 4096;
    const short* Kbase = kh + (size_t)bh * 65536;
    const short* Vbase = vh + (size_t)bh * 65536;

    // stage Q -> [0], K0 -> [4096], V0 -> [8192] (shorts)
    #pragma unroll
    for (int s = 0; s < 4; s++) {
        int ci = s * 128 + tid;
        int lo = (s * 128 + wave * 64) * 8;
        async16((const int4*)Qg + ci,    lds + lo);
        async16((const int4*)Kbase + ci, lds + 4096 + lo);
        async16((const int4*)Vbase + ci, lds + 8192 + lo);
    }
    __syncthreads();

    int row_q = wave * 32 + m;           // this lane's q-row (local)

    bf16x8 qb[4];                        // Q as B-operand: n=qrow, k=d
    #pragma unroll
    for (int st = 0; st < 4; st++)
        qb[st] = *(const bf16x8*)&lds[row_q * 64 + (((half + 2 * st) ^ sw) * 8)];

    const bf16x8 ones = {16256,16256,16256,16256,16256,16256,16256,16256};

    f32x16 O0, O1, Lacc;
    #pragma unroll
    for (int r = 0; r < 16; r++) { O0[r] = 0.f; O1[r] = 0.f; Lacc[r] = 0.f; }

    for (int kt = 0; kt <= qt; kt++) {
        if (kt > 0) __syncthreads();     // drains this tile's DMA; frees other buf
        if (kt < qt) {                   // async prefetch kt+1 behind compute
            const short* Kg = Kbase + (size_t)(kt + 1) * 4096;
            const short* Vg = Vbase + (size_t)(kt + 1) * 4096;
            int koff = 4096 + ((kt + 1) & 1) * 8192;
            #pragma unroll
            for (int s = 0; s < 4; s++) {
                int ci = s * 128 + tid;
                int lo = (s * 128 + wave * 64) * 8;
                async16((const int4*)Kg + ci, lds + koff + lo);
                async16((const int4*)Vg + ci, lds + koff + 4096 + lo);
            }
        }
        const short* Kb = lds + 4096 + (kt & 1) * 8192;
        const short* Vb = Kb + 4096;

        // S^T[key][qrow]: A = K rows (key), B = Q regs. 2 key-blocks.
        f32x16 s0, s1;
        #pragma unroll
        for (int r = 0; r < 16; r++) { s0[r] = 0.f; s1[r] = 0.f; }
        #pragma unroll
        for (int st = 0; st < 4; st++) {
            int co = ((half + 2 * st) ^ sw) * 8;
            bf16x8 ka0 = *(const bf16x8*)&Kb[m * 64 + co];
            bf16x8 ka1 = *(const bf16x8*)&Kb[(32 + m) * 64 + co];
            s0 = __builtin_amdgcn_mfma_f32_32x32x16_bf16(ka0, qb[st], s0, 0, 0, 0);
            s1 = __builtin_amdgcn_mfma_f32_32x32x16_bf16(ka1, qb[st], s1, 0, 0, 0);
        }

        if (kt == qt) {                  // causal mask on diagonal tile
            #pragma unroll
            for (int r = 0; r < 16; r++) {
                int ko = (r & 3) + 8 * (r >> 2) + 4 * half;
                if (ko > row_q)      s0[r] = -INFINITY;
                if (32 + ko > row_q) s1[r] = -INFINITY;
            }
        }

        // p = exp2(s - 20) -> P[qrow][key] packed b64 (own rows; no barrier)
        #pragma unroll
        for (int t = 0; t < 4; t++) {
            int2 v0, v1;
            v0.x = pack2(f2bf_fast(__builtin_amdgcn_exp2f(s0[4*t+0] - 20.f)),
                         f2bf_fast(__builtin_amdgcn_exp2f(s0[4*t+1] - 20.f)));
            v0.y = pack2(f2bf_fast(__builtin_amdgcn_exp2f(s0[4*t+2] - 20.f)),
                         f2bf_fast(__builtin_amdgcn_exp2f(s0[4*t+3] - 20.f)));
            v1.x = pack2(f2bf_fast(__builtin_amdgcn_exp2f(s1[4*t+0] - 20.f)),
                         f2bf_fast(__builtin_amdgcn_exp2f(s1[4*t+1] - 20.f)));
            v1.y = pack2(f2bf_fast(__builtin_amdgcn_exp2f(s1[4*t+2] - 20.f)),
                         f2bf_fast(__builtin_amdgcn_exp2f(s1[4*t+3] - 20.f)));
            *(int2*)&lds[row_q * 64 + ((t       ^ sw) * 8) + 4 * half] = v0;
            *(int2*)&lds[row_q * 64 + (((4 + t) ^ sw) * 8) + 4 * half] = v1;
        }

        bf16x8 pa[4];                    // P as A-operand: m=qrow, k=key
        #pragma unroll
        for (int st = 0; st < 4; st++)
            pa[st] = *(const bf16x8*)&lds[row_q * 64 + (((half + 2 * st) ^ sw) * 8)];

        // Lacc += P.1 ; O += P V (2 d-blocks)
        #pragma unroll
        for (int st = 0; st < 4; st++) {
            int co = ((half + 2 * st) ^ sw) * 8;
            bf16x8 vb0 = *(const bf16x8*)&Vb[m * 64 + co];
            bf16x8 vb1 = *(const bf16x8*)&Vb[(32 + m) * 64 + co];
            Lacc = __builtin_amdgcn_mfma_f32_32x32x16_bf16(pa[st], ones, Lacc, 0, 0, 0);
            O0   = __builtin_amdgcn_mfma_f32_32x32x16_bf16(pa[st], vb0,  O0,  0, 0, 0);
            O1   = __builtin_amdgcn_mfma_f32_32x32x16_bf16(pa[st], vb1,  O1,  0, 0, 0);
        }
    }

    // epilogue: normalize, transpose via padded LDS -> ot[B,C,L] bf16
    float inv[16];
    #pragma unroll
    for (int r = 0; r < 16; r++) inv[r] = 1.f / Lacc[r];

    __syncthreads();                     // all waves done with K/V buffers
    short* Eb = lds + 4096;              // 64 d-rows x stride 72
    #pragma unroll
    for (int t = 0; t < 4; t++) {
        int qoff = 8 * t + 4 * half;     // O rows (qrow) for regs 4t..4t+3
        int2 v0, v1;
        v0.x = pack2(f2bf_fast(O0[4*t+0] * inv[4*t+0]), f2bf_fast(O0[4*t+1] * inv[4*t+1]));
        v0.y = pack2(f2bf_fast(O0[4*t+2] * inv[4*t+2]), f2bf_fast(O0[4*t+3] * inv[4*t+3]));
        v1.x = pack2(f2bf_fast(O1[4*t+0] * inv[4*t+0]), f2bf_fast(O1[4*t+1] * inv[4*t+1]));
        v1.y = pack2(f2bf_fast(O1[4*t+2] * inv[4*t+2]), f2bf_fast(O1[4*t+3] * inv[4*t+3]));
        *(int2*)&Eb[m * 72        + wave * 32 + qoff] = v0;   // d = m
        *(int2*)&Eb[(32 + m) * 72 + wave * 32 + qoff] = v1;   // d = 32+m
    }
    __syncthreads();
    #pragma unroll
    for (int jj = 0; jj < 4; jj++) {
        int i = tid + jj * 128;          // < 512
        int d = i >> 3, seg = i & 7;
        int4 v = *(const int4*)&Eb[d * 72 + seg * 8];
        *(int4*)(ot + ((size_t)(b * C) + h * 64 + d) * L + qt * 64 + seg * 8) = v;
    }
}

// ---------------------------------------------------------------------------
// Residual + LayerNorm, single pass (x cached in regs), coalesced along L.
// ot [B,C,L] bf16; q fp32 [B,C,L]; y fp32 [B,C,L]. WG = (b, 32-l chunk).
// ---------------------------------------------------------------------------
__global__ __launch_bounds__(512) void ln_kernel(
    const short* __restrict__ ot, const float* __restrict__ q,
    const float* __restrict__ gamma, const float* __restrict__ beta,
    float* __restrict__ y)
{
    int bx = blockIdx.x;
    int tile = bx & 31;                  // L/32
    int b = bx >> 5;
    int l0 = tile * 32;
    int tid = threadIdx.x;
    int li_ = tid & 31, cs = tid >> 5;   // cs in 0..15, 32 channels each

    __shared__ float sp[16][33], ssp[16][33];
    __shared__ float mu_s[32], rs_s[32];

    size_t base = ((size_t)b * C + cs * 32) * L + l0 + li_;
    const short* otp = ot + base;
    const float* qp  = q + base;

    float xr[32];
    float s = 0.f, ss = 0.f;
    #pragma unroll
    for (int cc = 0; cc < 32; cc++) {
        float x = bfs2f(otp[(size_t)cc * L]) + qp[(size_t)cc * L];
        xr[cc] = x;
        s += x; ss += x * x;
    }
    sp[cs][li_] = s; ssp[cs][li_] = ss;
    __syncthreads();
    if (tid < 32) {
        float t1 = 0.f, t2 = 0.f;
        #pragma unroll
        for (int j = 0; j < 16; j++) { t1 += sp[j][tid]; t2 += ssp[j][tid]; }
        float mean = t1 * (1.f / 512.f);
        float var  = t2 * (1.f / 512.f) - mean * mean;
        mu_s[tid] = mean;
        rs_s[tid] = rsqrtf(var + 1e-5f);
    }
    __syncthreads();
    float mu = mu_s[li_], rs = rs_s[li_];
    float* yp = y + base;
    #pragma unroll
    for (int cc = 0; cc < 32; cc++) {
        int c = cs * 32 + cc;
        yp[(size_t)cc * L] = (xr[cc] - mu) * rs * gamma[c] + beta[c];
    }
}

// ---------------------------------------------------------------------------
extern "C" void kernel_launch(void* const* d_in, const int* in_sizes, int n_in,
                              void* d_out, int out_size, void* d_ws, size_t ws_size,
                              hipStream_t stream)
{
    const float* q     = (const float*)d_in[0];
    const float* k     = (const float*)d_in[1];
    // d_in[2] = mask — analytic
    const float* wq    = (const float*)d_in[3];
    const float* wk    = (const float*)d_in[4];
    const float* wv    = (const float*)d_in[5];
    const float* gamma = (const float*)d_in[6];
    const float* beta  = (const float*)d_in[7];
    float* y = (float*)d_out;

    const size_t N = (size_t)B * H * L * D;      // 4,194,304
    short* qh  = (short*)d_ws;                   // [BH][16][64 rows][8-chunk swz]
    short* kh  = qh + N;                         // same layout
    short* vh  = kh + N;                         // [BH][16][d 64][l-chunk swz]
    short* ot  = vh + N;                         // [B, C, L] bf16 (transposed o)
    short* wtg = ot + N;                         // 294912 bf16 A-frag weights

    wprep_kernel<<<1152, 256, 0, stream>>>(wq, wk, wv, wtg);
    conv_kernel<<<2 * B * H * (L / 64), 256, 0, stream>>>(q, k, wtg, qh, kh, vh);
    flash_kernel<<<B * H * (L / 64), 128, 0, stream>>>(qh, kh, vh, ot);
    ln_kernel<<<B * (L / 32), 512, 0, stream>>>(ot, q, gamma, beta, y);
}